// Round 1
// baseline (48.562 us; speedup 1.0000x reference)
//
#include <hip/hip_runtime.h>

// Problem constants (match reference)
#define N1 8192
#define N2 8192
#define D  8

// Kernel 1: row sums of input1 (N1 x D) and input2 (N2 x D) into ws.
// ws[0..N1-1] = s1, ws[N1..N1+N2-1] = s2.
__global__ void rbf_rowsum_kernel(const float* __restrict__ in1,
                                  const float* __restrict__ in2,
                                  float* __restrict__ s) {
    int idx = blockIdx.x * blockDim.x + threadIdx.x;
    if (idx < N1) {
        const float4* p = reinterpret_cast<const float4*>(in1 + (size_t)idx * D);
        float4 a = p[0];
        float4 b = p[1];
        s[idx] = ((a.x + a.y) + (a.z + a.w)) + ((b.x + b.y) + (b.z + b.w));
    } else if (idx < N1 + N2) {
        int j = idx - N1;
        const float4* p = reinterpret_cast<const float4*>(in2 + (size_t)j * D);
        float4 a = p[0];
        float4 b = p[1];
        s[N1 + j] = ((a.x + a.y) + (a.z + a.w)) + ((b.x + b.y) + (b.z + b.w));
    }
}

// Kernel 2: out[i, j] = exp((s1[i] - s2[j])^2) * gamma, float4-vectorized on j.
// grid = (N2 / (256*4), N1), block = 256. One float4 store per thread.
__global__ void __launch_bounds__(256)
rbf_main_kernel(const float* __restrict__ s,
                const float* __restrict__ gamma_p,
                float4* __restrict__ out) {
    const int i  = blockIdx.y;
    const int j4 = blockIdx.x * blockDim.x + threadIdx.x;   // float4 index along row

    const float s1i = s[i];          // wave-uniform -> scalar load
    const float g   = gamma_p[0];    // wave-uniform -> scalar load

    const float4 s2v = reinterpret_cast<const float4*>(s + N1)[j4];  // L1/L2 hit

    float4 r;
    {
        float d0 = s1i - s2v.x;
        float d1 = s1i - s2v.y;
        float d2 = s1i - s2v.z;
        float d3 = s1i - s2v.w;
        r.x = __expf(d0 * d0) * g;
        r.y = __expf(d1 * d1) * g;
        r.z = __expf(d2 * d2) * g;
        r.w = __expf(d3 * d3) * g;
    }

    out[(size_t)i * (N2 / 4) + j4] = r;
}

extern "C" void kernel_launch(void* const* d_in, const int* in_sizes, int n_in,
                              void* d_out, int out_size, void* d_ws, size_t ws_size,
                              hipStream_t stream) {
    const float* in1     = (const float*)d_in[0];
    const float* in2     = (const float*)d_in[1];
    const float* gamma_p = (const float*)d_in[2];
    float* ws  = (float*)d_ws;                 // needs (N1+N2)*4 = 64 KB
    float4* out = (float4*)d_out;

    // Kernel 1: 16384 threads total
    {
        const int threads = 256;
        const int total   = N1 + N2;
        const int blocks  = (total + threads - 1) / threads;
        rbf_rowsum_kernel<<<blocks, threads, 0, stream>>>(in1, in2, ws);
    }

    // Kernel 2: one float4 per thread
    {
        dim3 block(256);
        dim3 grid(N2 / (256 * 4), N1);         // (8, 8192)
        rbf_main_kernel<<<grid, block, 0, stream>>>(ws, gamma_p, out);
    }
}